// Round 6
// baseline (1709.970 us; speedup 1.0000x reference)
//
#include <hip/hip_runtime.h>

#define SEQ 365
#define BS  2048
#define HS  64
#define IND 32
#define XXC 5
#define CH  8    // time-steps per staged input chunk

typedef float f32x2 __attribute__((ext_vector_type(2)));

// R1-measured-best MAC form. Safe here because each wave's live set fits the
// forced 128-reg budget -> everything arch-resident -> "v" constraints free.
#define PKFMA(acc, a, b) asm("v_pk_fma_f32 %0, %1, %2, %0" : "+v"(acc) : "v"(a), "v"(b))

__device__ __forceinline__ float rcp_(float x) { return __builtin_amdgcn_rcpf(x); }
__device__ __forceinline__ float sig_(float x) { return rcp_(1.0f + __expf(-x)); }
__device__ __forceinline__ float tanh_(float x) { return 1.0f - 2.0f * rcp_(1.0f + __expf(2.0f * x)); }

// ---------------- Fused 3-wave gate-split TimeLSTM, v2 -------------------
// R5 diagnosis: (a) 32 wave-uniform x s_loads issued+consumed per step ->
// 1-2 cold HBM misses (~900cy) on the serial path every step (9490 cy/step,
// VALU 38%); (b) launch_bounds(192,1) let the allocator target ~6-8 waves
// -> 64-reg budget -> weights AGPR-parked + copied (307 vs ~105 issues).
// Fixes: (1) x/xx/td staged in 8-step LDS chunks, issue-early(ts=0)/
// write-late(ts=4), zero per-step global loads; (2) waves_per_eu(4,8)
// pins budget at 512/4=128 >= ~125 live/lane (staging on wave 2 to
// balance); >=4 waves/SIMD so other blocks fill barrier bubbles.
__global__ __attribute__((amdgpu_flat_work_group_size(192, 192), amdgpu_waves_per_eu(4, 8)))
void tlstm_fused3(const float* __restrict__ x_for_h,
                  const float* __restrict__ x_for_x,
                  const float* __restrict__ td_in,
                  const float* __restrict__ Wx,    // [32][192]
                  const float* __restrict__ Wxm,   // [5][128]
                  const float* __restrict__ Wh,    // [64][192]
                  const float* __restrict__ Wt1,   // [64]
                  const float* __restrict__ Wt,    // [128]
                  const float* __restrict__ bias,  // [320]
                  float* __restrict__ out)
{
    __shared__ __align__(8)  float hb[3][2][HS];      // per-wave h ping-pong (no cross-wave h)
    __shared__ float gb[2][5][HS];                    // [par][i,c,o,t1,t2][lane]
    __shared__ __align__(16) float xs[2][CH * IND];   // x chunks
    __shared__ float xxs[2][CH * XXC];
    __shared__ float tds[2][CH];

    const int tid = threadIdx.x;
    const int g   = tid >> 6;        // 0: i-gate(+t1), 1: c_app-gate(+t2,+xx/td stage), 2: o-gate(+x stage,+out)
    const int j   = tid & 63;
    const int b   = blockIdx.x;
    const int col = g * 64 + j;

    // gate column slices: Wh 32 pairs (64 regs) + Wx 16 pairs (32 regs)
    f32x2 whp[32];
#pragma unroll
    for (int m = 0; m < 32; ++m)
        whp[m] = {Wh[(2 * m) * 192 + col], Wh[(2 * m + 1) * 192 + col]};
    f32x2 wxp[16];
#pragma unroll
    for (int m = 0; m < 16; ++m)
        wxp[m] = {Wx[(2 * m) * 192 + col], Wx[(2 * m + 1) * 192 + col]};

    const float bg   = (g == 0) ? bias[j] : (g == 1) ? bias[192 + j] : bias[256 + j];
    const float wtB  = Wt[64 + j];             // g==2
    const float wt1j = fminf(Wt1[j], 0.0f);    // g==0
    const float wtA  = Wt[j];                  // g==1
    const float bm   = (g == 1) ? bias[128 + j] : bias[64 + j];
    float wm[XXC];                             // g==0: Wxm[:, :64]; g==1: Wxm[:, 64:]
#pragma unroll
    for (int k = 0; k < XXC; ++k)
        wm[k] = (g == 1) ? Wxm[k * 128 + 64 + j] : Wxm[k * 128 + j];

    const float* xhb = x_for_h + (size_t)b * SEQ * IND;
    const float* xxb = x_for_x + (size_t)b * SEQ * XXC;
    const float* tdp = td_in + (size_t)b * SEQ;
    float* outp = out + (size_t)b * SEQ * HS + j;

    const int jd5 = j / XXC, jm5 = j - jd5 * XXC;   // xx staging map (lanes < 40)
    const int xr  = j >> 3,  xc4 = j & 7;           // x staging map (1 float4/lane)

    // ---- stage chunk 0 directly ----
    if (g == 2) {
        float4 v = *(const float4*)(xhb + (size_t)xr * IND + xc4 * 4);
        *(float4*)&xs[0][j * 4] = v;
    } else if (g == 1) {
        if (j < CH * XXC)              xxs[0][j]      = xxb[j];
        else if (j >= 48 && j < 48+CH) tds[0][j - 48] = tdp[j - 48];
    }
    hb[g][0][j] = 0.0f;
    __syncthreads();

    float c = 0.0f, hfin = 0.0f;

    // xp for t=0 (x-part + bias), from LDS
    float xp;
    {
        const f32x2* xq = (const f32x2*)&xs[0][0];
        f32x2 x0 = {bg, 0.0f}, x1 = {0.0f, 0.0f};
#pragma unroll
        for (int m = 0; m < 16; m += 2) {
            PKFMA(x0, xq[m],     wxp[m]);
            PKFMA(x1, xq[m + 1], wxp[m + 1]);
        }
        xp = x0.x + x0.y + x1.x + x1.y;
    }

    float4 sx4;                 // wave-2 staging regs (live ts=0..4)
    float  sxx = 0.0f, stdv = 0.0f;  // wave-1 staging regs

    for (int t = 0; t < SEQ; ++t) {
        const int par = t & 1;
        const int cb  = (t >> 3) & 1;
        const int ts  = t & 7;
        const float td = tds[cb][ts];

        // ---- pre-barrier: own-gate h-matmul + t1/t2 ----
        const f32x2* hp = (const f32x2*)hb[g][par];
        f32x2 a0 = {0.0f, 0.0f}, a1 = {0.0f, 0.0f};
#pragma unroll
        for (int m = 0; m < 32; m += 2) {
            PKFMA(a0, hp[m],     whp[m]);
            PKFMA(a1, hp[m + 1], whp[m + 1]);
        }
        float ag = xp + (a0.x + a0.y) + (a1.x + a1.y);
        if (g == 2) ag = fmaf(td, wtB, ag);
        gb[par][g][j] = ag;
        if (g == 0) {
            float am = bm;
            const float* x5 = &xxs[cb][ts * XXC];
#pragma unroll
            for (int k = 0; k < XXC; ++k) am = fmaf(x5[k], wm[k], am);
            gb[par][3][j] = sig_(am + tanh_(td * wt1j));
        } else if (g == 1) {
            float am = bm;
            const float* x5 = &xxs[cb][ts * XXC];
#pragma unroll
            for (int k = 0; k < XXC; ++k) am = fmaf(x5[k], wm[k], am);
            gb[par][4][j] = sig_(am + tanh_(td * wtA));
        }

        __syncthreads();

        // ---- post-barrier: gate math (redundant per wave), h update ----
        const float ai  = gb[par][0][j];
        const float acg = gb[par][1][j];
        const float aog = gb[par][2][j];
        const float t1v = gb[par][3][j];
        const float t2v = gb[par][4][j];

        const float i_t  = sig_(ai);
        const float capp = tanh_(acg);
        const float it1  = i_t * t1v;
        const float ctl  = sig_(fmaf(it1, capp - c, c));           // sig(c + i*t1*(capp-c))
        const float cn   = sig_(fmaf(i_t, fmaf(t2v, capp, -c), c)); // sig(c + i*(t2*capp-c))
        const float o_t  = sig_(aog);
        const float hn   = o_t + tanh_(ctl);

        hb[g][par ^ 1][j] = hn;            // own copy; same-wave in-order read next step
        if (g == 2) outp[(size_t)t * HS] = hn;
        hfin = hn; c = cn;

        // staging: issue-early at ts==0 for chunk [t+8, t+16), write-late at ts==4
        if (ts == 0 && t + CH < SEQ) {
            const int t0 = t + CH;
            if (g == 2) {
                const int r = min(t0 + xr, SEQ - 1);
                sx4 = *(const float4*)(xhb + (size_t)r * IND + xc4 * 4);
            } else if (g == 1) {
                if (j < CH * XXC)              sxx  = xxb[(size_t)min(t0 + jd5, SEQ - 1) * XXC + jm5];
                else if (j >= 48 && j < 48+CH) stdv = tdp[min(t0 + (j - 48), SEQ - 1)];
            }
        }
        if (ts == 4 && t + 4 < SEQ) {
            const int nb = cb ^ 1;
            if (g == 2) {
                *(float4*)&xs[nb][j * 4] = sx4;
            } else if (g == 1) {
                if (j < CH * XXC)              xxs[nb][j]      = sxx;
                else if (j >= 48 && j < 48+CH) tds[nb][j - 48] = stdv;
            }
        }

        // xp for t+1 (independent of h_t -> post-barrier filler)
        if (t + 1 < SEQ) {
            const int ncb = ((t + 1) >> 3) & 1;
            const int nts = (t + 1) & 7;
            const f32x2* xq = (const f32x2*)&xs[ncb][nts * IND];
            f32x2 x0 = {bg, 0.0f}, x1 = {0.0f, 0.0f};
#pragma unroll
            for (int m = 0; m < 16; m += 2) {
                PKFMA(x0, xq[m],     wxp[m]);
                PKFMA(x1, xq[m + 1], wxp[m + 1]);
            }
            xp = x0.x + x0.y + x1.x + x1.y;
        }
    }

    if (g == 2) {
        float* hT = out + (size_t)BS * SEQ * HS;
        float* cT = hT + (size_t)BS * HS;
        hT[(size_t)b * HS + j] = hfin;
        cT[(size_t)b * HS + j] = c;
    }
}

extern "C" void kernel_launch(void* const* d_in, const int* in_sizes, int n_in,
                              void* d_out, int out_size, void* d_ws, size_t ws_size,
                              hipStream_t stream)
{
    const float* x_for_h = (const float*)d_in[0];
    const float* x_for_x = (const float*)d_in[1];
    const float* TimeDiff = (const float*)d_in[2];
    const float* weights_x = (const float*)d_in[3];
    const float* weights_x_maintained = (const float*)d_in[4];
    const float* weights_h = (const float*)d_in[5];
    const float* weights_t1 = (const float*)d_in[6];
    const float* weights_t = (const float*)d_in[7];
    const float* bias = (const float*)d_in[8];
    float* out = (float*)d_out;

    tlstm_fused3<<<BS, 192, 0, stream>>>(x_for_h, x_for_x, TimeDiff,
                                         weights_x, weights_x_maintained, weights_h,
                                         weights_t1, weights_t, bias, out);
}